// Round 20
// baseline (100.283 us; speedup 1.0000x reference)
//
#include <hip/hip_runtime.h>
#include <hip/hip_bf16.h>

#define IN_H  224
#define IN_W  224
#define OUT_H 218
#define OUT_W 218
#define NCH   64
#define PLANE (OUT_H * OUT_W)
#define RSH   464            // bf16 tile row stride (ushorts)
#define CP1   232            // copy1 offset within row (ushorts)
#define NROW  4              // output rows per block
#define NYB   55             // ceil(218/4)
#define NMT   4              // channel groups of 16
#define OCH   876            // obuf per-plane stride (872 data + 4 pad)
#define NBLK  (32 * NMT * NYB)   // 7040 = 8 XCDs * 880 -> bijective chunk map

typedef short bf16x8 __attribute__((ext_vector_type(8)));
typedef float f32x4  __attribute__((ext_vector_type(4)));

__device__ inline unsigned int f2bf(float f) {   // RNE f32 -> bf16 (cold path)
    unsigned int u = __builtin_bit_cast(unsigned int, f);
    return (u + 0x7fffu + ((u >> 16) & 1u)) >> 16;
}

__device__ inline unsigned int pk2(float lo, float hi) {  // v_cvt_pk path (proven R12+)
    __hip_bfloat162 h2 = __float22bfloat162_rn(make_float2(lo, hi));
    unsigned int u;
    __builtin_memcpy(&u, &h2, sizeof(u));
    return u;
}

// Pack weights into MFMA A-fragments (bf16, 7x7 zero-padded to 8x8). Verified R5-R18.
// [fc = mt*2+kt][lane]: ch = 16*mt + (lane&15), dy = 4*kt + (lane>>4),
// word j = {dx=2j (lo), dx=2j+1 (hi)}.
__global__ __launch_bounds__(512) void repack_w(const float* __restrict__ wgt,
                                                unsigned int* __restrict__ wa) {
    const int t    = threadIdx.x;
    const int lane = t & 63;
    const int fc   = t >> 6;
    const int mt   = fc >> 1, kt = fc & 1;
    const int ch   = 16 * mt + (lane & 15);
    const int dy   = 4 * kt + (lane >> 4);
    unsigned int w[4];
#pragma unroll
    for (int j = 0; j < 4; ++j) {
        float lo = (dy < 7 && 2 * j     < 7) ? wgt[ch * 49 + dy * 7 + 2 * j]     : 0.f;
        float hi = (dy < 7 && 2 * j + 1 < 7) ? wgt[ch * 49 + dy * 7 + 2 * j + 1] : 0.f;
        w[j] = f2bf(lo) | (f2bf(hi) << 16);
    }
    reinterpret_cast<uint4*>(wa)[fc * 64 + lane] = make_uint4(w[0], w[1], w[2], w[3]);
}

// R17 structure (86.7us, best): block = (n, mt, 4 rows), bf16 dual-copy tile,
// 3488B contiguous dwordx4 store runs, y-innermost bijective XCD map.
// R20 change (= R19 intent): output stores NON-TEMPORAL (no L2 allocate) —
// output is write-once/never-read. Uses ext_vector f32x4 (HIP float4 is
// rejected by the builtin).
__global__ __launch_bounds__(512) void conv7x7_row(
    const float* __restrict__ in,
    const unsigned int* __restrict__ wa,
    float* __restrict__ out)
{
    __shared__ unsigned short tbf[10 * RSH];  //  9280 B: bf16 rows, dual copy
    __shared__ float obuf[16 * OCH];          // 56064 B: 16 planes x (4x218)

    const int tid  = threadIdx.x;
    const int lane = tid & 63;
    const int wid  = tid >> 6;
    const int g    = lane >> 4;           // k-group -> dy / channel sub-row
    const int c    = lane & 15;           // pixel-in-group

    // Chunked XCD map (bijective: 7040 = 8*880): XCD k gets 4 whole images,
    // y-innermost so adjacent ranks extend the same planes' runs.
    const int bid  = blockIdx.x;
    const int rank = (bid & 7) * (NBLK / 8) + (bid >> 3);
    const int n    = rank / (NMT * NYB);
    const int rem  = rank - n * (NMT * NYB);
    const int mt   = rem / NYB;
    const int yb   = rem - mt * NYB;
    const int y0   = yb * NROW;           // <= 216

    // ---- stationary A-fragments for this channel group ----
    union AB { uint4 u; bf16x8 v; };
    AB af[2];
    const uint4* wa4 = reinterpret_cast<const uint4*>(wa);
#pragma unroll
    for (int kt = 0; kt < 2; ++kt) af[kt].u = wa4[(mt * 2 + kt) * 64 + lane];

    // ---- stage 10 rows, bf16 dual-copy, float4 loads, pad folded in ----
    const float* inb = in + (size_t)n * (IN_H * IN_W);
    for (int idx = tid; idx < 10 * 58; idx += 512) {
        int r = idx / 58, c4 = idx - r * 58;            // cols 4c4..4c4+3 (<=231)
        int iny = min(y0 + r, IN_H - 1);
        const float* rp = inb + iny * IN_W;
        float4 v = (c4 < 56) ? *reinterpret_cast<const float4*>(rp + 4 * c4)
                             : make_float4(0.f, 0.f, 0.f, 0.f);
        float nx = (c4 < 55) ? rp[4 * c4 + 4] : 0.f;    // elem 224.. = pad 0
        uint2 w0 = make_uint2(pk2(v.x, v.y), pk2(v.z, v.w));        // copy0
        uint2 w1 = make_uint2(pk2(v.y, v.z), pk2(v.w, nx));         // copy1 (+1 shift)
        *reinterpret_cast<uint2*>(&tbf[r * RSH + 4 * c4])       = w0;
        *reinterpret_cast<uint2*>(&tbf[r * RSH + CP1 + 4 * c4]) = w1;
    }
    __syncthreads();

    // ---- compute: 56 (row r, strip s) pairs over 8 waves = 7 each ----
    const int sh = c & 1;
    for (int k = wid; k < 4 * 14; k += 8) {
        const int r  = k / 14;
        const int x0 = 16 * (k - 14 * r);
        const int e0 = x0 + c - sh;       // even element start

        AB bf[2];
#pragma unroll
        for (int kt = 0; kt < 2; ++kt) {
            // row r+4kt+g; index 10 (only r=3,kt=1,g=3) carries zero weights ->
            // clamp to 9 (finite data x 0 = 0).
            const int row = min(r + 4 * kt + g, 9);
            const unsigned int* p = reinterpret_cast<const unsigned int*>(
                &tbf[row * RSH + sh * CP1 + e0]);
            union { unsigned int u[4]; uint4 q; } bb;
            bb.u[0] = p[0]; bb.u[1] = p[1]; bb.u[2] = p[2]; bb.u[3] = p[3];
            bf[kt].u = bb.q;
        }

        f32x4 acc = {0.f, 0.f, 0.f, 0.f};
        acc = __builtin_amdgcn_mfma_f32_16x16x32_bf16(af[0].v, bf[0].v, acc, 0, 0, 0);
        acc = __builtin_amdgcn_mfma_f32_16x16x32_bf16(af[1].v, bf[1].v, acc, 0, 0, 0);

        // obuf[plane=4g+rr][row r][col]; mask col>=218
        if (x0 + c < OUT_W) {
#pragma unroll
            for (int rr = 0; rr < 4; ++rr)
                obuf[(4 * g + rr) * OCH + r * OUT_W + x0 + c] = acc[rr];
        }
    }
    __syncthreads();

    // ---- store: wave w -> planes 2w,2w+1; each plane one 3488B contiguous
    //      16B-aligned run = 218 dwordx4 (109 for the 2-row tail block).
    //      NON-TEMPORAL via ext_vector f32x4 (no L2 allocate). ----
    const int vrows = min(NROW, OUT_H - y0);
    const int nf4   = (vrows * OUT_W) >> 2;        // 218 or 109
    const size_t base = ((size_t)(n * NCH + 16 * mt)) * PLANE + (size_t)y0 * OUT_W;
#pragma unroll
    for (int i = 0; i < 2; ++i) {
        const int p = 2 * wid + i;
        const float* src = &obuf[p * OCH];
        float* dst = out + base + (size_t)p * PLANE;
#pragma unroll
        for (int j = 0; j < 4; ++j) {
            int idx = 64 * j + lane;
            if (idx < nf4) {
                f32x4 v = *reinterpret_cast<const f32x4*>(src + 4 * idx);
                __builtin_nontemporal_store(v, reinterpret_cast<f32x4*>(dst + 4 * idx));
            }
        }
    }
}

extern "C" void kernel_launch(void* const* d_in, const int* in_sizes, int n_in,
                              void* d_out, int out_size, void* d_ws, size_t ws_size,
                              hipStream_t stream) {
    const float* in  = (const float*)d_in[0];
    const float* wgt = (const float*)d_in[1];
    float* out = (float*)d_out;
    unsigned int* wa = (unsigned int*)d_ws;   // 8*64*16 = 8192 B

    repack_w<<<1, 512, 0, stream>>>(wgt, wa);
    conv7x7_row<<<NBLK, 512, 0, stream>>>(in, wa, out);
}

// Round 21
// 92.574 us; speedup vs baseline: 1.0833x; 1.0833x over previous
//
#include <hip/hip_runtime.h>
#include <hip/hip_bf16.h>

#define IN_H  224
#define IN_W  224
#define OUT_H 218
#define OUT_W 218
#define NCH   64
#define PLANE (OUT_H * OUT_W)
#define RSH   464            // bf16 tile row stride (ushorts)
#define CP1   232            // copy1 offset within row (ushorts)
#define NROW  8              // output rows per block (two 4-row passes)
#define NYB   28             // ceil(218/8): 27 full + 2-row tail
#define NMT   4              // channel groups of 16
#define OCH   876            // obuf per-plane stride (872 data + 4 pad)
#define NBLK  (32 * NMT * NYB)   // 3584 = 8 XCDs * 448 -> bijective chunk map

typedef short bf16x8 __attribute__((ext_vector_type(8)));
typedef float f32x4  __attribute__((ext_vector_type(4)));

__device__ inline unsigned int f2bf(float f) {   // RNE f32 -> bf16 (cold path)
    unsigned int u = __builtin_bit_cast(unsigned int, f);
    return (u + 0x7fffu + ((u >> 16) & 1u)) >> 16;
}

__device__ inline unsigned int pk2(float lo, float hi) {  // v_cvt_pk path (proven R12+)
    __hip_bfloat162 h2 = __float22bfloat162_rn(make_float2(lo, hi));
    unsigned int u;
    __builtin_memcpy(&u, &h2, sizeof(u));
    return u;
}

// lgkm-only barrier: LDS ops retired; global stores stay in flight.
__device__ inline void bar_lgkm() {
    asm volatile("s_waitcnt lgkmcnt(0)" ::: "memory");
    __builtin_amdgcn_sched_barrier(0);
    __builtin_amdgcn_s_barrier();
    __builtin_amdgcn_sched_barrier(0);
}

// Pack weights into MFMA A-fragments (bf16, 7x7 zero-padded to 8x8). Verified R5-R20.
// [fc = mt*2+kt][lane]: ch = 16*mt + (lane&15), dy = 4*kt + (lane>>4),
// word j = {dx=2j (lo), dx=2j+1 (hi)}.
__global__ __launch_bounds__(512) void repack_w(const float* __restrict__ wgt,
                                                unsigned int* __restrict__ wa) {
    const int t    = threadIdx.x;
    const int lane = t & 63;
    const int fc   = t >> 6;
    const int mt   = fc >> 1, kt = fc & 1;
    const int ch   = 16 * mt + (lane & 15);
    const int dy   = 4 * kt + (lane >> 4);
    unsigned int w[4];
#pragma unroll
    for (int j = 0; j < 4; ++j) {
        float lo = (dy < 7 && 2 * j     < 7) ? wgt[ch * 49 + dy * 7 + 2 * j]     : 0.f;
        float hi = (dy < 7 && 2 * j + 1 < 7) ? wgt[ch * 49 + dy * 7 + 2 * j + 1] : 0.f;
        w[j] = f2bf(lo) | (f2bf(hi) << 16);
    }
    reinterpret_cast<uint4*>(wa)[fc * 64 + lane] = make_uint4(w[0], w[1], w[2], w[3]);
}

// R17 machinery + two-pass 8-row block: storeB extends storeA's per-plane runs
// to 6976 contiguous bytes (the only lever with consistent dose-response).
// Regular stores (NT hurt, R20); lgkm-only barriers keep stores in flight.
__global__ __launch_bounds__(512) void conv7x7_row(
    const float* __restrict__ in,
    const unsigned int* __restrict__ wa,
    float* __restrict__ out)
{
    __shared__ unsigned short tbf[10 * RSH];  //  9280 B: bf16 rows, dual copy
    __shared__ float obuf[16 * OCH];          // 56064 B: 16 planes x (4x218)

    const int tid  = threadIdx.x;
    const int lane = tid & 63;
    const int wid  = tid >> 6;
    const int g    = lane >> 4;
    const int c    = lane & 15;

    // Chunked XCD map (bijective: 3584 = 8*448), y-innermost.
    const int bid  = blockIdx.x;
    const int rank = (bid & 7) * (NBLK / 8) + (bid >> 3);
    const int n    = rank / (NMT * NYB);
    const int rem  = rank - n * (NMT * NYB);
    const int mt   = rem / NYB;
    const int yb   = rem - mt * NYB;
    const int y0   = yb * NROW;           // 0..216

    // ---- stationary A-fragments ----
    union AB { uint4 u; bf16x8 v; };
    AB af[2];
    const uint4* wa4 = reinterpret_cast<const uint4*>(wa);
#pragma unroll
    for (int kt = 0; kt < 2; ++kt) af[kt].u = wa4[(mt * 2 + kt) * 64 + lane];

    const float* inb = in + (size_t)n * (IN_H * IN_W);
    const int sh = c & 1;

    // ---- stage macro: rows Y0S..Y0S+9 as bf16 dual-copy (clamped) ----
#define STAGE(Y0S)                                                             \
    for (int idx = tid; idx < 10 * 58; idx += 512) {                           \
        int r = idx / 58, c4 = idx - r * 58;                                   \
        int iny = min((Y0S) + r, IN_H - 1);                                    \
        const float* rp = inb + iny * IN_W;                                    \
        float4 v = (c4 < 56) ? *reinterpret_cast<const float4*>(rp + 4 * c4)   \
                             : make_float4(0.f, 0.f, 0.f, 0.f);                \
        float nx = (c4 < 55) ? rp[4 * c4 + 4] : 0.f;                           \
        uint2 w0 = make_uint2(pk2(v.x, v.y), pk2(v.z, v.w));                   \
        uint2 w1 = make_uint2(pk2(v.y, v.z), pk2(v.w, nx));                    \
        *reinterpret_cast<uint2*>(&tbf[r * RSH + 4 * c4])       = w0;          \
        *reinterpret_cast<uint2*>(&tbf[r * RSH + CP1 + 4 * c4]) = w1;          \
    }

    // ---- compute macro: 56 (r,strip) iters over 8 waves into obuf ----
#define COMPUTE                                                                \
    for (int k = wid; k < 56; k += 8) {                                        \
        const int r  = k / 14;                                                 \
        const int x0 = 16 * (k - 14 * r);                                      \
        const int e0 = x0 + c - sh;                                            \
        AB bf[2];                                                              \
        _Pragma("unroll")                                                      \
        for (int kt = 0; kt < 2; ++kt) {                                       \
            const int row = min(r + 4 * kt + g, 9);                            \
            const unsigned int* p = reinterpret_cast<const unsigned int*>(     \
                &tbf[row * RSH + sh * CP1 + e0]);                              \
            union { unsigned int u[4]; uint4 q; } bb;                          \
            bb.u[0] = p[0]; bb.u[1] = p[1]; bb.u[2] = p[2]; bb.u[3] = p[3];    \
            bf[kt].u = bb.q;                                                   \
        }                                                                      \
        f32x4 acc = {0.f, 0.f, 0.f, 0.f};                                      \
        acc = __builtin_amdgcn_mfma_f32_16x16x32_bf16(af[0].v, bf[0].v, acc, 0, 0, 0); \
        acc = __builtin_amdgcn_mfma_f32_16x16x32_bf16(af[1].v, bf[1].v, acc, 0, 0, 0); \
        if (x0 + c < OUT_W) {                                                  \
            _Pragma("unroll")                                                  \
            for (int rr = 0; rr < 4; ++rr)                                     \
                obuf[(4 * g + rr) * OCH + r * OUT_W + x0 + c] = acc[rr];       \
        }                                                                      \
    }

    // ---- store macro: wave -> planes 2w,2w+1 at rows Y0S.., nf4 dwordx4 ----
#define STORE4(Y0S, NF4)                                                       \
    {                                                                          \
        const size_t base = ((size_t)(n * NCH + 16 * mt)) * PLANE              \
                          + (size_t)(Y0S) * OUT_W;                             \
        _Pragma("unroll")                                                      \
        for (int i = 0; i < 2; ++i) {                                          \
            const int p = 2 * wid + i;                                         \
            const float* src = &obuf[p * OCH];                                 \
            float* dst = out + base + (size_t)p * PLANE;                       \
            _Pragma("unroll")                                                  \
            for (int j = 0; j < 4; ++j) {                                      \
                int idx = 64 * j + lane;                                       \
                if (idx < (NF4))                                               \
                    *reinterpret_cast<float4*>(dst + 4 * idx) =                \
                        *reinterpret_cast<const float4*>(src + 4 * idx);       \
            }                                                                  \
        }                                                                      \
    }

    // ---- pass A: rows y0..y0+3 ----
    STAGE(y0)
    __syncthreads();                      // no stores in flight yet
    COMPUTE
    bar_lgkm();                           // obuf A complete; tile reads retired
    const int nf4A = (min(NROW/2, OUT_H - y0) * OUT_W) >> 2;   // 218 or 109
    STORE4(y0, nf4A)                      // issue stores (stay in flight)

    // ---- pass B: rows y0+4..y0+7 (skipped at the 2-row tail) ----
    if (y0 + 4 < OUT_H) {
        STAGE(y0 + 4)                     // restage tile (disjoint from obuf reads)
        bar_lgkm();                       // storeA obuf-reads retired; tile ready
        COMPUTE
        bar_lgkm();                       // obuf B complete
        STORE4(y0 + 4, 218)              // extends each plane's run to 6976B
    }

#undef STAGE
#undef COMPUTE
#undef STORE4
}

extern "C" void kernel_launch(void* const* d_in, const int* in_sizes, int n_in,
                              void* d_out, int out_size, void* d_ws, size_t ws_size,
                              hipStream_t stream) {
    const float* in  = (const float*)d_in[0];
    const float* wgt = (const float*)d_in[1];
    float* out = (float*)d_out;
    unsigned int* wa = (unsigned int*)d_ws;   // 8*64*16 = 8192 B

    repack_w<<<1, 512, 0, stream>>>(wgt, wa);
    conv7x7_row<<<NBLK, 512, 0, stream>>>(in, wa, out);
}

// Round 22
// 83.462 us; speedup vs baseline: 1.2015x; 1.1092x over previous
//
#include <hip/hip_runtime.h>
#include <hip/hip_bf16.h>

#define IN_H  224
#define IN_W  224
#define OUT_H 218
#define OUT_W 218
#define NCH   64
#define PLANE (OUT_H * OUT_W)
#define RSH   464            // bf16 tile row stride (ushorts)
#define CP1   232            // copy1 offset within row (ushorts)
#define NROW  4              // output rows per block
#define NYB   55             // ceil(218/4)
#define NMT   4              // channel groups of 16
#define OCH   876            // obuf per-plane stride (872 data + 4 pad)
#define NBLK  (32 * NMT * NYB)   // 7040 = 8 XCDs * 880 -> bijective chunk map

typedef short bf16x8 __attribute__((ext_vector_type(8)));
typedef float f32x4  __attribute__((ext_vector_type(4)));

__device__ inline unsigned int pk2(float lo, float hi) {  // RNE packed cvt (proven R12+)
    __hip_bfloat162 h2 = __float22bfloat162_rn(make_float2(lo, hi));
    unsigned int u;
    __builtin_memcpy(&u, &h2, sizeof(u));
    return u;
}

// lgkm-only barrier: LDS ops retired; global stores stay in flight.
__device__ inline void bar_lgkm() {
    asm volatile("s_waitcnt lgkmcnt(0)" ::: "memory");
    __builtin_amdgcn_sched_barrier(0);
    __builtin_amdgcn_s_barrier();
    __builtin_amdgcn_sched_barrier(0);
}

// R17 structure (86.7us, best of 21 rounds) with the weight repack FUSED:
// no repack kernel, no d_ws, no serial launch + graph gap. Each block
// cooperatively loads its 16 channels' raw weights (784 f32) into the head
// of obuf (dead until compute), then each lane builds its 2 A-fragments
// in-register. A-frag mapping (verified R5-R21): ch = 16*mt + (lane&15),
// dy = 4*kt + (lane>>4), word j = {dx=2j, dx=2j+1}; dy==7 / dx==7 -> 0.
__global__ __launch_bounds__(512) void conv7x7_row(
    const float* __restrict__ in,
    const float* __restrict__ wgt,
    float* __restrict__ out)
{
    __shared__ unsigned short tbf[10 * RSH];  //  9280 B: bf16 rows, dual copy
    __shared__ float obuf[16 * OCH];          // 56064 B: 16 planes x (4x218)

    const int tid  = threadIdx.x;
    const int lane = tid & 63;
    const int wid  = tid >> 6;
    const int g    = lane >> 4;           // k-group -> dy / channel sub-row
    const int c    = lane & 15;           // pixel-in-group

    // Chunked XCD map (bijective: 7040 = 8*880): XCD k gets 4 whole images,
    // y-innermost so adjacent ranks extend the same planes' runs.
    const int bid  = blockIdx.x;
    const int rank = (bid & 7) * (NBLK / 8) + (bid >> 3);
    const int n    = rank / (NMT * NYB);
    const int rem  = rank - n * (NMT * NYB);
    const int mt   = rem / NYB;
    const int yb   = rem - mt * NYB;
    const int y0   = yb * NROW;           // <= 216

    // ---- phase 0a: cooperative raw-weight load into obuf scratch ----
    const float* wsrc = wgt + mt * (16 * 49);
    for (int idx = tid; idx < 784; idx += 512) obuf[idx] = wsrc[idx];

    // ---- phase 0b: stage 10 rows, bf16 dual-copy, float4 loads ----
    const float* inb = in + (size_t)n * (IN_H * IN_W);
    for (int idx = tid; idx < 10 * 58; idx += 512) {
        int r = idx / 58, c4 = idx - r * 58;            // cols 4c4..4c4+3 (<=231)
        int iny = min(y0 + r, IN_H - 1);
        const float* rp = inb + iny * IN_W;
        float4 v = (c4 < 56) ? *reinterpret_cast<const float4*>(rp + 4 * c4)
                             : make_float4(0.f, 0.f, 0.f, 0.f);
        float nx = (c4 < 55) ? rp[4 * c4 + 4] : 0.f;    // elem 224.. = pad 0
        uint2 w0 = make_uint2(pk2(v.x, v.y), pk2(v.z, v.w));        // copy0
        uint2 w1 = make_uint2(pk2(v.y, v.z), pk2(v.w, nx));         // copy1 (+1 shift)
        *reinterpret_cast<uint2*>(&tbf[r * RSH + 4 * c4])       = w0;
        *reinterpret_cast<uint2*>(&tbf[r * RSH + CP1 + 4 * c4]) = w1;
    }
    __syncthreads();

    // ---- phase 0c: build stationary A-fragments from obuf scratch ----
    union AB { uint4 u; bf16x8 v; };
    AB af[2];
    {
        const int c16 = lane & 15;
#pragma unroll
        for (int kt = 0; kt < 2; ++kt) {
            const int dy = 4 * kt + g;
            if (dy < 7) {
                const float* wr = &obuf[c16 * 49 + dy * 7];
                af[kt].u = make_uint4(pk2(wr[0], wr[1]), pk2(wr[2], wr[3]),
                                      pk2(wr[4], wr[5]), pk2(wr[6], 0.f));
            } else {
                af[kt].u = make_uint4(0u, 0u, 0u, 0u);
            }
        }
    }
    __syncthreads();   // all weight ds_reads retired before compute overwrites obuf

    // ---- compute: 56 (row r, strip s) pairs over 8 waves = 7 each ----
    const int sh = c & 1;
    for (int k = wid; k < 4 * 14; k += 8) {
        const int r  = k / 14;
        const int x0 = 16 * (k - 14 * r);
        const int e0 = x0 + c - sh;       // even element start

        AB bf[2];
#pragma unroll
        for (int kt = 0; kt < 2; ++kt) {
            // row r+4kt+g; index 10 (only r=3,kt=1,g=3) carries zero weights ->
            // clamp to 9 (finite data x 0 = 0).
            const int row = min(r + 4 * kt + g, 9);
            const unsigned int* p = reinterpret_cast<const unsigned int*>(
                &tbf[row * RSH + sh * CP1 + e0]);
            union { unsigned int u[4]; uint4 q; } bb;
            bb.u[0] = p[0]; bb.u[1] = p[1]; bb.u[2] = p[2]; bb.u[3] = p[3];
            bf[kt].u = bb.q;
        }

        f32x4 acc = {0.f, 0.f, 0.f, 0.f};
        acc = __builtin_amdgcn_mfma_f32_16x16x32_bf16(af[0].v, bf[0].v, acc, 0, 0, 0);
        acc = __builtin_amdgcn_mfma_f32_16x16x32_bf16(af[1].v, bf[1].v, acc, 0, 0, 0);

        // obuf[plane=4g+rr][row r][col]; mask col>=218
        if (x0 + c < OUT_W) {
#pragma unroll
            for (int rr = 0; rr < 4; ++rr)
                obuf[(4 * g + rr) * OCH + r * OUT_W + x0 + c] = acc[rr];
        }
    }
    bar_lgkm();

    // ---- store: wave w -> planes 2w,2w+1; each plane one 3488B contiguous
    //      16B-aligned run = 218 dwordx4 (109 for the 2-row tail block) ----
    const int vrows = min(NROW, OUT_H - y0);
    const int nf4   = (vrows * OUT_W) >> 2;        // 218 or 109
    const size_t base = ((size_t)(n * NCH + 16 * mt)) * PLANE + (size_t)y0 * OUT_W;
#pragma unroll
    for (int i = 0; i < 2; ++i) {
        const int p = 2 * wid + i;
        const float* src = &obuf[p * OCH];
        float* dst = out + base + (size_t)p * PLANE;
#pragma unroll
        for (int j = 0; j < 4; ++j) {
            int idx = 64 * j + lane;
            if (idx < nf4)
                *reinterpret_cast<float4*>(dst + 4 * idx) =
                    *reinterpret_cast<const float4*>(src + 4 * idx);
        }
    }
}

extern "C" void kernel_launch(void* const* d_in, const int* in_sizes, int n_in,
                              void* d_out, int out_size, void* d_ws, size_t ws_size,
                              hipStream_t stream) {
    const float* in  = (const float*)d_in[0];
    const float* wgt = (const float*)d_in[1];
    float* out = (float*)d_out;

    conv7x7_row<<<NBLK, 512, 0, stream>>>(in, wgt, out);
}